// Round 1
// baseline (48.734 us; speedup 1.0000x reference)
//
#include <hip/hip_runtime.h>
#include <hip/hip_bf16.h>
#include <math.h>

// Sizes (fixed by the reference)
#define NL 3      // layers
#define NB 128    // batch
#define NO 64     // objects
#define ND 64     // emb dim
#define NQ 32     // preds per pair
#define NP 4032   // 64*63 ordered pairs

typedef __bf16 bf16x8 __attribute__((ext_vector_type(8)));
typedef float  f32x4  __attribute__((ext_vector_type(4)));

__device__ __forceinline__ float sigm(float x) {
  return __builtin_amdgcn_rcpf(1.0f + __expf(-x));
}

// ---------------------------------------------------------------------------
// Kernel 1: precompute
//   blocks 0..127   : b-block -> mean[b], M[l][b][d] = mean.W1c + b1 ; exact e copy
//   blocks 128..133 : (l,half) -> Ut[l][o][d] = emb[o].W1a_row_d ; Vt likewise
// ---------------------------------------------------------------------------
__global__ __launch_bounds__(256) void precomp_k(
    const int* __restrict__ ids, const float* __restrict__ emb,
    const float* __restrict__ W1, const float* __restrict__ b1,
    float* __restrict__ Ut, float* __restrict__ Vt, float* __restrict__ M,
    float* __restrict__ e_out)
{
  const int blk = blockIdx.x, tid = threadIdx.x;

  if (blk < NB) {
    __shared__ int   ids_s[NO];
    __shared__ float psum[4][ND];
    __shared__ float mean_s[ND];
    const int b = blk;
    if (tid < NO) ids_s[tid] = ids[b * NO + tid];
    __syncthreads();

    {
      const int d = tid & 63, ng = tid >> 6;
      float s = 0.f;
#pragma unroll
      for (int nn = 0; nn < 16; ++nn) {
        const int n = ng * 16 + nn;
        const float v = emb[ids_s[n] * ND + d];
        e_out[(b * NO + n) * ND + d] = v;   // exact f32 copy of e
        s += v;
      }
      psum[ng][d] = s;
    }
    __syncthreads();
    if (tid < ND)
      mean_s[tid] = (psum[0][tid] + psum[1][tid] + psum[2][tid] + psum[3][tid]) * (1.0f / 64.0f);
    __syncthreads();

    if (tid < 192) {
      const int l = tid >> 6, d = tid & 63;
      const float* wrow = W1 + (l * ND + d) * 192 + 128;
      float acc = 0.f;
#pragma unroll
      for (int c4 = 0; c4 < 16; ++c4) {
        const f32x4 w = *(const f32x4*)(wrow + c4 * 4);
        const f32x4 m = *(const f32x4*)(&mean_s[c4 * 4]);
        acc += w[0] * m[0] + w[1] * m[1] + w[2] * m[2] + w[3] * m[3];
      }
      M[(l * NB + b) * ND + d] = acc + b1[l * ND + d];
    }
  } else {
    const int idx = blk - NB;
    const int l = idx >> 1, half = idx & 1;
    __shared__ float e_s[NO][68];   // padded to break bank alignment
    {
      const int o = tid >> 2, c0 = (tid & 3) * 16;
      const float* er = emb + o * ND + c0;
#pragma unroll
      for (int c = 0; c < 16; c += 4)
        *(f32x4*)(&e_s[o][c0 + c]) = *(const f32x4*)(er + c);
    }
    __syncthreads();

    const int d = tid & 63, og = tid >> 6;   // each thread: 16 objects x 1 d
    const float* wrow = W1 + (l * ND + d) * 192 + half * 64;
    float acc[16];
#pragma unroll
    for (int k = 0; k < 16; ++k) acc[k] = 0.f;
#pragma unroll
    for (int c4 = 0; c4 < 16; ++c4) {
      const f32x4 w = *(const f32x4*)(wrow + c4 * 4);
#pragma unroll
      for (int oo = 0; oo < 16; ++oo) {
        const f32x4 e = *(const f32x4*)(&e_s[og * 16 + oo][c4 * 4]);  // broadcast
        acc[oo] += e[0] * w[0] + e[1] * w[1] + e[2] * w[2] + e[3] * w[3];
      }
    }
    float* T = half ? Vt : Ut;
#pragma unroll
    for (int oo = 0; oo < 16; ++oo)
      T[(l * NO + og * 16 + oo) * ND + d] = acc[oo];
  }
}

// ---------------------------------------------------------------------------
// Kernel 2: main. grid = 3*128*2 = 768 (blk = l*256 + b*2 + ic), 256 threads.
// Per block: stage Vb (bf16, XOR-swizzled) + UpM (f32, padded) in LDS, then a
// barrier-free i-loop: build A-frag in regs, 4x mfma 16x16x32 bf16, sigmoid,
// predicated store (skip j==i).
// ---------------------------------------------------------------------------
__global__ __launch_bounds__(256) void main_k(
    const int* __restrict__ ids, const float* __restrict__ W2,
    const float* __restrict__ b2,
    const float* __restrict__ Ut, const float* __restrict__ Vt,
    const float* __restrict__ M, float* __restrict__ out)
{
  __shared__ float UpM_s[NO * 68];                 // Ut[ids[i]] + M[l][b], padded
  __shared__ __align__(16) __bf16 Vb_s[NO * 64];   // bf16(Vt[ids[j]]), XOR-swizzled

  const int blk = blockIdx.x, tid = threadIdx.x;
  const int ic = blk & 1, b = (blk >> 1) & 127, l = blk >> 8;

  // ---- phase A: stage ----
  {
    const int j = tid >> 2, kq = (tid & 3) * 16;
    const int oid = ids[b * NO + j];
    const float* vrow = Vt + (l * NO + oid) * ND + kq;
    const float* urow = Ut + (l * NO + oid) * ND + kq;
    const float* mrow = M + (l * NB + b) * ND + kq;
    f32x4 vv[4];
#pragma unroll
    for (int c = 0; c < 4; ++c) {
      vv[c] = *(const f32x4*)(vrow + c * 4);
      const f32x4 u = *(const f32x4*)(urow + c * 4);
      const f32x4 m = *(const f32x4*)(mrow + c * 4);
      *(f32x4*)(&UpM_s[j * 68 + kq + c * 4]) = u + m;
    }
    const int swz = (j & 7) << 4;
#pragma unroll
    for (int c = 0; c < 2; ++c) {
      bf16x8 pk;
#pragma unroll
      for (int e = 0; e < 4; ++e) pk[e] = (__bf16)vv[2 * c][e];
#pragma unroll
      for (int e = 0; e < 4; ++e) pk[4 + e] = (__bf16)vv[2 * c + 1][e];
      const int byteoff = j * 128 + (((kq + c * 8) * 2) ^ swz);
      *(bf16x8*)((char*)Vb_s + byteoff) = pk;
    }
  }

  // ---- B fragments (registers, per lane) ----
  const int lane = tid & 63;
  const int qlo = lane & 15, g = lane >> 4;
  bf16x8 bfrag[2][2];
  float b2v[2];
#pragma unroll
  for (int qt = 0; qt < 2; ++qt) {
    b2v[qt] = b2[l * NQ + qt * 16 + qlo];
#pragma unroll
    for (int kt = 0; kt < 2; ++kt) {
      const float* w2p = W2 + (l * NQ + qt * 16 + qlo) * ND + kt * 32 + g * 8;
      const f32x4 w0 = *(const f32x4*)(w2p);
      const f32x4 w1v = *(const f32x4*)(w2p + 4);
      bf16x8 bf;
#pragma unroll
      for (int e = 0; e < 4; ++e) bf[e] = (__bf16)w0[e];
#pragma unroll
      for (int e = 0; e < 4; ++e) bf[4 + e] = (__bf16)w1v[e];
      bfrag[qt][kt] = bf;
    }
  }
  __syncthreads();

  // ---- phase B: barrier-free i-loop ----
  const int wave = tid >> 6;
  const int j0 = wave * 16;              // this wave's 16-row j-tile
  const int jA = j0 + qlo;               // A-operand row for this lane
  const int swzA = (jA & 7) << 4;
  const char* vbase = (const char*)Vb_s + jA * 128;
  const int i0 = ic * 32;

  for (int ii = 0; ii < 32; ++ii) {
    const int i = i0 + ii;
    const float* upm = &UpM_s[i * 68];

    bf16x8 a[2];
#pragma unroll
    for (int kt = 0; kt < 2; ++kt) {
      const int k0 = g * 8 + kt * 32;
      const bf16x8 v8 = *(const bf16x8*)(vbase + ((k0 * 2) ^ swzA));
      const f32x4 r0 = *(const f32x4*)(upm + k0);
      const f32x4 r1 = *(const f32x4*)(upm + k0 + 4);
      bf16x8 t;
      t[0] = (__bf16)fmaxf((float)v8[0] + r0[0], 0.0f);
      t[1] = (__bf16)fmaxf((float)v8[1] + r0[1], 0.0f);
      t[2] = (__bf16)fmaxf((float)v8[2] + r0[2], 0.0f);
      t[3] = (__bf16)fmaxf((float)v8[3] + r0[3], 0.0f);
      t[4] = (__bf16)fmaxf((float)v8[4] + r1[0], 0.0f);
      t[5] = (__bf16)fmaxf((float)v8[5] + r1[1], 0.0f);
      t[6] = (__bf16)fmaxf((float)v8[6] + r1[2], 0.0f);
      t[7] = (__bf16)fmaxf((float)v8[7] + r1[3], 0.0f);
      a[kt] = t;
    }

    const f32x4 z = {0.f, 0.f, 0.f, 0.f};
    f32x4 acc0 = __builtin_amdgcn_mfma_f32_16x16x32_bf16(a[0], bfrag[0][0], z, 0, 0, 0);
    acc0 = __builtin_amdgcn_mfma_f32_16x16x32_bf16(a[1], bfrag[0][1], acc0, 0, 0, 0);
    f32x4 acc1 = __builtin_amdgcn_mfma_f32_16x16x32_bf16(a[0], bfrag[1][0], z, 0, 0, 0);
    acc1 = __builtin_amdgcn_mfma_f32_16x16x32_bf16(a[1], bfrag[1][1], acc1, 0, 0, 0);

    float* pb = out + ((size_t)(l * NB + b) * NP + (size_t)i * 63) * NQ;
#pragma unroll
    for (int r = 0; r < 4; ++r) {
      const int jrow = j0 + g * 4 + r;       // D row = 4*(lane>>4) + r
      if (jrow != i) {
        const int p_in_i = (jrow < i) ? jrow : jrow - 1;
        float* o0 = pb + p_in_i * NQ + qlo;  // D col = lane&15
        o0[0]  = sigm(acc0[r] + b2v[0]);
        o0[16] = sigm(acc1[r] + b2v[1]);
      }
    }
  }
}

// ---------------------------------------------------------------------------
extern "C" void kernel_launch(void* const* d_in, const int* in_sizes, int n_in,
                              void* d_out, int out_size, void* d_ws, size_t ws_size,
                              hipStream_t stream) {
  const int*   ids = (const int*)d_in[0];
  const float* emb = (const float*)d_in[1];
  const float* W1  = (const float*)d_in[2];
  const float* b1  = (const float*)d_in[3];
  const float* W2  = (const float*)d_in[4];
  const float* b2  = (const float*)d_in[5];
  float* out = (float*)d_out;

  float* Ut = (float*)d_ws;              // [3][64][64] f32
  float* Vt = Ut + NL * NO * ND;         // [3][64][64] f32
  float* M  = Vt + NL * NO * ND;         // [3][128][64] f32  (total 192 KB of ws)
  float* e_out = out + (size_t)NL * NB * NP * NQ;  // e appended after preds

  precomp_k<<<NB + 2 * NL, 256, 0, stream>>>(ids, emb, W1, b1, Ut, Vt, M, e_out);
  main_k<<<NL * NB * 2, 256, 0, stream>>>(ids, W2, b2, Ut, Vt, M, out);
}